// Round 10
// baseline (1002.813 us; speedup 1.0000x reference)
//
#include <hip/hip_runtime.h>

// ---------------------------------------------------------------------------
// TrajectoryDecoder: B=4096, F=256, H=256, M=3, T=30 (T read from device)
// out = [trajectories (B,M,T,2) fp32][mode_probs (B,M) fp32]
// R24: de-correlation retry. R23 analysis: 52% stall = correlated waits (both
// waves/SIMD in one block, lockstep barriers). R16 (32-row x 4-wave blocks,
// 2 independent blocks/CU) failed on L2 saturation at 3.0 MB/step/CU; gxc
// (R23) cut the stream 23% -> 2.3 MB/step/CU ~ 66% of per-XCD L2 BW. This
// kernel = R16's proven skeleton + R23's gxc: L0 h-side only, gxc_rz in LDS
// (32KB/block), gxc_xn in global L2 (16KB/block; XCD stream 3.3MB < 4MB L2),
// single h0, 5 barriers/step. LDS 80,128B -> 2 blocks/CU; per-CU MFMA work
// == R23. 384 blocks (128 CUs x2 + 128 x1; pace = 2-block CUs + overlap).
// ws guard kept; fallback = verbatim R14 decoder_base.
// ---------------------------------------------------------------------------

typedef __attribute__((ext_vector_type(8))) short bf16x8;
typedef __attribute__((ext_vector_type(4))) short short4n;
typedef __attribute__((ext_vector_type(4))) float f32x4;

__device__ __forceinline__ short f2bf(float f) {
    unsigned u = __builtin_bit_cast(unsigned, f);
    unsigned r = (u + 0x7fffu + ((u >> 16) & 1u)) >> 16;
    return (short)r;
}
__device__ __forceinline__ float bf2f(short s) {
    unsigned u = ((unsigned)(unsigned short)s) << 16;
    return __builtin_bit_cast(float, u);
}
__device__ __forceinline__ float fast_sigmoid(float x) {
    x = fminf(fmaxf(x, -30.f), 30.f);
    float e = __builtin_amdgcn_exp2f(x * -1.442695041f);
    return __builtin_amdgcn_rcpf(1.f + e);
}
__device__ __forceinline__ float fast_tanh(float x) {
    x = fminf(fmaxf(x, -15.f), 15.f);
    float e = __builtin_amdgcn_exp2f(x * -2.885390082f);
    return (1.f - e) * __builtin_amdgcn_rcpf(1.f + e);
}

// ---------------------------------------------------------------------------
// Weight prep: fp32 -> bf16, B-fragment consumption order (R14 layout).
// Tiles are 16-col x 32-k fragments, row-count independent -> reused as-is.
//   P0  [0,1152):    w_hh0 per (m,wg): 48 = [rz: ks*4+t (32)][n: 32+ks*2+nt]
//   P1  [1152,3456): per (m,wg): 96 = [rz: half*32+ks*4+t (64)]
//                                     [xn: 64+ks*2+nt][hn: 80+ks*2+nt]
//   PC  [3456,4608): w_ih0[:,2:258] per (m,wg): 48 = [ks*6+t6]
// gxc_xn region: [4608*512, +384*8*4*256) shorts
// ---------------------------------------------------------------------------
__global__ void prep_kernel(const float* __restrict__ w_ih0,
                            const float* __restrict__ w_hh0,
                            const float* __restrict__ w_ih1,
                            const float* __restrict__ w_hh1,
                            short* __restrict__ ws) {
    int bid = blockIdx.x;
    int L = threadIdx.x;
    const float* src;
    int srcRowLen, colBase, m, w, ks, t;
    if (bid < 1152) {
        int idx = bid, mw = idx / 48, blk = idx % 48;
        m = mw / 8; w = mw % 8;
        if (blk < 32) { ks = blk >> 2; t = blk & 3; }
        else { int q = blk - 32; ks = q >> 1; t = 4 + (q & 1); }
        src = w_hh0 + (size_t)m * 768 * 256; srcRowLen = 256; colBase = 0;
    } else if (bid < 3456) {
        int idx = bid - 1152, mw = idx / 96, blk = idx % 96;
        m = mw / 8; w = mw % 8;
        int half;
        if (blk < 64) { half = blk >> 5; ks = (blk >> 2) & 7; t = blk & 3; }
        else { int q = blk - 64; half = q >> 4; ks = (q >> 1) & 7; t = 4 + (q & 1); }
        src = (half ? w_hh1 : w_ih1) + (size_t)m * 768 * 256;
        srcRowLen = 256; colBase = 0;
    } else {
        int idx = bid - 3456, mw = idx / 48, blk = idx % 48;
        m = mw / 8; w = mw % 8; ks = blk / 6; t = blk % 6;
        src = w_ih0 + (size_t)m * 768 * 258; srcRowLen = 258; colBase = 2;
    }
    int row = (t >> 1) * 256 + 32 * w + (t & 1) * 16 + (L & 15);
    int col0 = colBase + ks * 32 + (L >> 4) * 8;
    short* dst = ws + (size_t)bid * 512 + L * 8;
    const float* s = src + (size_t)row * srcRowLen + col0;
#pragma unroll
    for (int j = 0; j < 8; ++j) dst[j] = f2bf(s[j]);
}

// ---------------------------------------------------------------------------
// Mode-probability MLP
// ---------------------------------------------------------------------------
__global__ __launch_bounds__(256) void modeprobs_kernel(
    const float* __restrict__ ctx, const float* __restrict__ w1,
    const float* __restrict__ b1, const float* __restrict__ w2,
    const float* __restrict__ b2, float* __restrict__ out,
    long probs_off) {
    __shared__ float w1s[64 * 256];
    int tid = threadIdx.x;
    int j = tid & 63;
    int rsub = tid >> 6;
#pragma unroll
    for (int i = 0; i < 64; ++i) w1s[tid + i * 256] = w1[tid + i * 256];
    float b1v = b1[j];
    float w2v0 = w2[j], w2v1 = w2[64 + j], w2v2 = w2[128 + j];
    float b20 = b2[0], b21 = b2[1], b22 = b2[2];
    __syncthreads();
    for (int c = 0; c < 16; ++c) {
        int brow = blockIdx.x * 64 + c * 4 + rsub;
        const float* crow = ctx + (size_t)brow * 256;
        float accv = b1v;
#pragma unroll 8
        for (int k = 0; k < 256; ++k) {
            int kk = (k + j) & 255;
            accv += w1s[j * 256 + kk] * crow[kk];
        }
        float h = fmaxf(accv, 0.f);
        float l0 = h * w2v0, l1 = h * w2v1, l2 = h * w2v2;
#pragma unroll
        for (int s = 1; s < 64; s <<= 1) {
            l0 += __shfl_xor(l0, s);
            l1 += __shfl_xor(l1, s);
            l2 += __shfl_xor(l2, s);
        }
        if (j == 0) {
            l0 += b20; l1 += b21; l2 += b22;
            float mx = fmaxf(l0, fmaxf(l1, l2));
            float e0 = __builtin_amdgcn_exp2f((l0 - mx) * 1.442695041f);
            float e1 = __builtin_amdgcn_exp2f((l1 - mx) * 1.442695041f);
            float e2 = __builtin_amdgcn_exp2f((l2 - mx) * 1.442695041f);
            float inv = 1.f / (e0 + e1 + e2);
            out[probs_off + (size_t)brow * 3 + 0] = e0 * inv;
            out[probs_off + (size_t)brow * 3 + 1] = e1 * inv;
            out[probs_off + (size_t)brow * 3 + 2] = e2 * inv;
        }
    }
}

// ---------------------------------------------------------------------------
// decoder_gxc32: 32 rows x 4 waves (256 thr); wave w owns col-groups
// wg = 2w, 2w+1 (cols [64w, 64w+64) per gate). gxc_rz in LDS, gxc_xn in
// global. Single h0; 5 barriers/step. 2 blocks/CU (LDS 80,128B).
// ---------------------------------------------------------------------------
__global__ __launch_bounds__(256, 2) void decoder_gxc32(
    const float* __restrict__ context,
    const float* __restrict__ w_ih0_f,
    const float* __restrict__ b_ih0, const float* __restrict__ b_hh0,
    const float* __restrict__ b_ih1, const float* __restrict__ b_hh1,
    const float* __restrict__ out_w, const float* __restrict__ out_b,
    short* ws, float* __restrict__ out,
    const int* __restrict__ pT, int tilesPerMode, int nwork) {
    __shared__ short h0s[32 * 264];          // single h0 (in-place update)
    __shared__ short h1s[32 * 264];
    __shared__ short gxcrz[8 * 8 * 256];     // [wg][frag t*2+rt][lane*4] bf16
    __shared__ float posD[64];
    __shared__ float owl[512];
    __shared__ short cwp0h[768], cwp1h[768]; // pos weights (bf16)
    __shared__ float cbA[512];               // prologue: b_ih0+b_hh0 (rz)
    __shared__ float cbXn[256];              // prologue: b_ih0 (n)
    __shared__ float cbh0n[256];             // per-step ahn init
    __shared__ float cb1A[512];
    __shared__ float cb1X[256];
    __shared__ float cb1H[256];

    // Bijective lane-balanced XCD mapping (<=2 modes per XCD).
    const int lane8 = blockIdx.x & 7, slot = blockIdx.x >> 3;
    const int q = nwork >> 3, r8 = nwork & 7;
    int start, cnt;
    if (lane8 < r8) { cnt = q + 1; start = lane8 * (q + 1); }
    else            { cnt = q;     start = r8 * (q + 1) + (lane8 - r8) * q; }
    if (slot >= cnt) return;
    const int wk = start + slot;
    const int m = wk / tilesPerMode;
    const int b0 = (wk - m * tilesPerMode) * 32;

    const int T = *pT;
    const int tid = threadIdx.x;
    const int lane = tid & 63, w = tid >> 6;       // w in [0,4)
    const int lr = lane & 15, quad = lane >> 4;

    if (tid < 64) posD[tid] = 0.f;
    owl[tid] = out_w[m * 512 + tid];
    owl[256 + tid] = out_w[m * 512 + 256 + tid];
    cbA[tid] = b_ih0[m * 768 + tid] + b_hh0[m * 768 + tid];
    cbA[256 + tid] = b_ih0[m * 768 + 256 + tid] + b_hh0[m * 768 + 256 + tid];
    cb1A[tid] = b_ih1[m * 768 + tid] + b_hh1[m * 768 + tid];
    cb1A[256 + tid] = b_ih1[m * 768 + 256 + tid] + b_hh1[m * 768 + 256 + tid];
    cbXn[tid] = b_ih0[m * 768 + 512 + tid];
    cbh0n[tid] = b_hh0[m * 768 + 512 + tid];
    cb1X[tid] = b_ih1[m * 768 + 512 + tid];
    cb1H[tid] = b_hh1[m * 768 + 512 + tid];
    for (int cc = tid; cc < 768; cc += 256) {
        cwp0h[cc] = f2bf(w_ih0_f[((size_t)m * 768 + cc) * 258 + 0]);
        cwp1h[cc] = f2bf(w_ih0_f[((size_t)m * 768 + cc) * 258 + 1]);
    }
#pragma unroll
    for (int i = 0; i < 32; ++i) {
        int idx = tid + i * 256;
        int rr = idx >> 8, k = idx & 255;
        short v = f2bf(context[(size_t)(b0 + rr) * 256 + k]);
        h0s[rr * 264 + k] = v;
        h1s[rr * 264 + k] = v;
    }
    const float ob0v = out_b[m * 2 + 0], ob1v = out_b[m * 2 + 1];

    // Weight region bases per col-group (wg = 2w+g2), R14 layout.
    const short* p0B[2];  // w_hh0
    const short* p1B[2];  // layer1 block
    const short* pcB[2];  // w_ih0 ctx cols (prologue only)
    short* gxB[2];        // global xn cache per group
#pragma unroll
    for (int g2 = 0; g2 < 2; ++g2) {
        const int wg = 2 * w + g2;
        p0B[g2] = ws + ((size_t)(m * 8 + wg) * 48) * 512 + lane * 8;
        p1B[g2] = ws + (size_t)1152 * 512 + ((size_t)(m * 8 + wg) * 96) * 512 + lane * 8;
        pcB[g2] = ws + (size_t)3456 * 512 + ((size_t)(m * 8 + wg) * 48) * 512 + lane * 8;
        gxB[g2] = ws + (size_t)4608 * 512 +
                  ((size_t)(wk * 8 + wg) * 4) * 256 + lane * 4;
    }

    __syncthreads();

    // ======== prologue: gxc = bias + ctx @ w_ih0[:,2:]^T (once) ========
    {
        f32x4 arz[2][4][2], axn[2][2][2];
#pragma unroll
        for (int g2 = 0; g2 < 2; ++g2) {
            const int cbase = 32 * (2 * w + g2) + lr;
#pragma unroll
            for (int t = 0; t < 4; ++t) {
                const int c = (t >> 1) * 256 + cbase + (t & 1) * 16;
                const float bb = cbA[c];
#pragma unroll
                for (int rt = 0; rt < 2; ++rt)
#pragma unroll
                    for (int r = 0; r < 4; ++r) arz[g2][t][rt][r] = bb;
            }
#pragma unroll
            for (int nt = 0; nt < 2; ++nt) {
                const float bx = cbXn[cbase + nt * 16];
#pragma unroll
                for (int rt = 0; rt < 2; ++rt)
#pragma unroll
                    for (int r = 0; r < 4; ++r) axn[g2][nt][rt][r] = bx;
            }
        }
        const short* bpc0 = pcB[0];
        const short* bpc1 = pcB[1];
#pragma unroll 1
        for (int ks = 0; ks < 8; ++ks) {
            bf16x8 ac[2];
#pragma unroll
            for (int rt = 0; rt < 2; ++rt)
                ac[rt] = *reinterpret_cast<const bf16x8*>(
                    h0s + (rt * 16 + lr) * 264 + ks * 32 + quad * 8);
#pragma unroll
            for (int g2 = 0; g2 < 2; ++g2) {
                const short* bpc = g2 ? bpc1 : bpc0;
#pragma unroll
                for (int t = 0; t < 4; ++t) {
                    bf16x8 b = *reinterpret_cast<const bf16x8*>(bpc + t * 512);
#pragma unroll
                    for (int rt = 0; rt < 2; ++rt)
                        arz[g2][t][rt] = __builtin_amdgcn_mfma_f32_16x16x32_bf16(
                            ac[rt], b, arz[g2][t][rt], 0, 0, 0);
                }
#pragma unroll
                for (int nt = 0; nt < 2; ++nt) {
                    bf16x8 b = *reinterpret_cast<const bf16x8*>(bpc + (4 + nt) * 512);
#pragma unroll
                    for (int rt = 0; rt < 2; ++rt)
                        axn[g2][nt][rt] = __builtin_amdgcn_mfma_f32_16x16x32_bf16(
                            ac[rt], b, axn[g2][nt][rt], 0, 0, 0);
                }
            }
            bpc0 += 6 * 512;
            bpc1 += 6 * 512;
        }
        // rz fragments -> LDS; xn fragments -> global
#pragma unroll
        for (int g2 = 0; g2 < 2; ++g2) {
            short* grz = gxcrz + ((2 * w + g2) * 8) * 256 + lane * 4;
#pragma unroll
            for (int t = 0; t < 4; ++t)
#pragma unroll
                for (int rt = 0; rt < 2; ++rt) {
                    short4n pk;
#pragma unroll
                    for (int r = 0; r < 4; ++r) pk[r] = f2bf(arz[g2][t][rt][r]);
                    *reinterpret_cast<short4n*>(grz + (t * 2 + rt) * 256) = pk;
                }
#pragma unroll
            for (int nt = 0; nt < 2; ++nt)
#pragma unroll
                for (int rt = 0; rt < 2; ++rt) {
                    short4n pk;
#pragma unroll
                    for (int r = 0; r < 4; ++r) pk[r] = f2bf(axn[g2][nt][rt][r]);
                    *reinterpret_cast<short4n*>(gxB[g2] + (nt * 2 + rt) * 256) = pk;
                }
        }
        asm volatile("s_waitcnt vmcnt(0)" ::: "memory");
    }
    __syncthreads();

    float cum0 = 0.f, cum1 = 0.f;

    for (int st = 0; st < T; ++st) {
        // ======== layer 0: h-side only (x-part cached) ========
        {
            int gxo = 0;
            asm volatile("" : "+v"(gxo));  // keep xn loads in-loop (no LICM)

            f32x4 arz[2][4][2], axn[2][2][2], ahn[2][2][2];
            float px[2][4], py[2][4];
#pragma unroll
            for (int rt = 0; rt < 2; ++rt)
#pragma unroll
                for (int rr = 0; rr < 4; ++rr) {
                    int row = rt * 16 + quad * 4 + rr;
                    px[rt][rr] = posD[row * 2];
                    py[rt][rr] = posD[row * 2 + 1];
                }
#pragma unroll
            for (int g2 = 0; g2 < 2; ++g2) {
                const int cbase = 32 * (2 * w + g2) + lr;
                const short* grz = gxcrz + ((2 * w + g2) * 8) * 256 + lane * 4;
                const short* gq = gxB[g2] + gxo;
#pragma unroll
                for (int t = 0; t < 4; ++t) {
                    const int c = (t >> 1) * 256 + cbase + (t & 1) * 16;
                    const float w0 = bf2f(cwp0h[c]), w1 = bf2f(cwp1h[c]);
#pragma unroll
                    for (int rt = 0; rt < 2; ++rt) {
                        short4n v = *reinterpret_cast<const short4n*>(
                            grz + (t * 2 + rt) * 256);
#pragma unroll
                        for (int r = 0; r < 4; ++r)
                            arz[g2][t][rt][r] = bf2f(v[r]) + px[rt][r] * w0 +
                                                py[rt][r] * w1;
                    }
                }
#pragma unroll
                for (int nt = 0; nt < 2; ++nt) {
                    const int cn = cbase + nt * 16;
                    const float w0 = bf2f(cwp0h[512 + cn]);
                    const float w1 = bf2f(cwp1h[512 + cn]);
                    const float bh = cbh0n[cn];
#pragma unroll
                    for (int rt = 0; rt < 2; ++rt) {
                        short4n v = *reinterpret_cast<const short4n*>(
                            gq + (nt * 2 + rt) * 256);
#pragma unroll
                        for (int r = 0; r < 4; ++r) {
                            axn[g2][nt][rt][r] = bf2f(v[r]) + px[rt][r] * w0 +
                                                 py[rt][r] * w1;
                            ahn[g2][nt][rt][r] = bh;
                        }
                    }
                }
            }
            const short* brz0 = p0B[0];
            const short* brz1 = p0B[1];
            const short* bn0 = p0B[0] + 32 * 512;
            const short* bn1 = p0B[1] + 32 * 512;
#pragma unroll 1
            for (int ks = 0; ks < 8; ++ks) {
                bf16x8 ah[2];
#pragma unroll
                for (int rt = 0; rt < 2; ++rt)
                    ah[rt] = *reinterpret_cast<const bf16x8*>(
                        h0s + (rt * 16 + lr) * 264 + ks * 32 + quad * 8);
#pragma unroll
                for (int g2 = 0; g2 < 2; ++g2) {
                    const short* brz = g2 ? brz1 : brz0;
                    const short* bn = g2 ? bn1 : bn0;
#pragma unroll
                    for (int t = 0; t < 4; ++t) {
                        bf16x8 b = *reinterpret_cast<const bf16x8*>(brz + t * 512);
#pragma unroll
                        for (int rt = 0; rt < 2; ++rt)
                            arz[g2][t][rt] = __builtin_amdgcn_mfma_f32_16x16x32_bf16(
                                ah[rt], b, arz[g2][t][rt], 0, 0, 0);
                    }
#pragma unroll
                    for (int nt = 0; nt < 2; ++nt) {
                        bf16x8 b = *reinterpret_cast<const bf16x8*>(bn + nt * 512);
#pragma unroll
                        for (int rt = 0; rt < 2; ++rt)
                            ahn[g2][nt][rt] = __builtin_amdgcn_mfma_f32_16x16x32_bf16(
                                ah[rt], b, ahn[g2][nt][rt], 0, 0, 0);
                    }
                }
                brz0 += 4 * 512; brz1 += 4 * 512;
                bn0 += 2 * 512;  bn1 += 2 * 512;
            }
            __syncthreads();  // B1a: all h0 reads complete (single buffer)
#pragma unroll
            for (int g2 = 0; g2 < 2; ++g2)
#pragma unroll
                for (int nt = 0; nt < 2; ++nt) {
                    const int col = 32 * (2 * w + g2) + nt * 16 + lr;
#pragma unroll
                    for (int rt = 0; rt < 2; ++rt)
#pragma unroll
                        for (int rr = 0; rr < 4; ++rr) {
                            int row = rt * 16 + quad * 4 + rr;
                            float rg = fast_sigmoid(arz[g2][nt][rt][rr]);
                            float zg = fast_sigmoid(arz[g2][2 + nt][rt][rr]);
                            float ng = fast_tanh(axn[g2][nt][rt][rr] +
                                                 rg * ahn[g2][nt][rt][rr]);
                            float hold = bf2f(h0s[row * 264 + col]);
                            h0s[row * 264 + col] =
                                f2bf((1.f - zg) * ng + zg * hold);
                        }
                }
        }
        __syncthreads();  // B1b: h0' visible

        // ======== layer 1 (merged rz+n) ========
        {
            f32x4 arz[2][4][2], axn[2][2][2], ahn[2][2][2];
#pragma unroll
            for (int g2 = 0; g2 < 2; ++g2) {
                const int cbase = 32 * (2 * w + g2) + lr;
#pragma unroll
                for (int t = 0; t < 4; ++t) {
                    const int c = (t >> 1) * 256 + cbase + (t & 1) * 16;
                    const float bb = cb1A[c];
#pragma unroll
                    for (int rt = 0; rt < 2; ++rt)
#pragma unroll
                        for (int rr = 0; rr < 4; ++rr)
                            arz[g2][t][rt][rr] = bb;
                }
#pragma unroll
                for (int nt = 0; nt < 2; ++nt) {
                    const int cn = cbase + nt * 16;
                    const float bx = cb1X[cn], bh = cb1H[cn];
#pragma unroll
                    for (int rt = 0; rt < 2; ++rt)
#pragma unroll
                        for (int rr = 0; rr < 4; ++rr) {
                            axn[g2][nt][rt][rr] = bx;
                            ahn[g2][nt][rt][rr] = bh;
                        }
                }
            }
            const short* bq00 = p1B[0];
            const short* bq01 = p1B[1];
            const short* bq10 = p1B[0] + 32 * 512;
            const short* bq11 = p1B[1] + 32 * 512;
            const short* bx0 = p1B[0] + 64 * 512;
            const short* bx1 = p1B[1] + 64 * 512;
            const short* bh0 = p1B[0] + 80 * 512;
            const short* bh1 = p1B[1] + 80 * 512;
#pragma unroll 1
            for (int ks = 0; ks < 8; ++ks) {
                bf16x8 a0[2], a1[2];
#pragma unroll
                for (int rt = 0; rt < 2; ++rt) {
                    a0[rt] = *reinterpret_cast<const bf16x8*>(
                        h0s + (rt * 16 + lr) * 264 + ks * 32 + quad * 8);
                    a1[rt] = *reinterpret_cast<const bf16x8*>(
                        h1s + (rt * 16 + lr) * 264 + ks * 32 + quad * 8);
                }
#pragma unroll
                for (int g2 = 0; g2 < 2; ++g2) {
                    const short* bq0 = g2 ? bq01 : bq00;
                    const short* bq1 = g2 ? bq11 : bq10;
                    const short* bxp = g2 ? bx1 : bx0;
                    const short* bhp = g2 ? bh1 : bh0;
#pragma unroll
                    for (int t = 0; t < 4; ++t) {
                        bf16x8 b = *reinterpret_cast<const bf16x8*>(bq0 + t * 512);
#pragma unroll
                        for (int rt = 0; rt < 2; ++rt)
                            arz[g2][t][rt] = __builtin_amdgcn_mfma_f32_16x16x32_bf16(
                                a0[rt], b, arz[g2][t][rt], 0, 0, 0);
                    }
#pragma unroll
                    for (int nt = 0; nt < 2; ++nt) {
                        bf16x8 b = *reinterpret_cast<const bf16x8*>(bxp + nt * 512);
#pragma unroll
                        for (int rt = 0; rt < 2; ++rt)
                            axn[g2][nt][rt] = __builtin_amdgcn_mfma_f32_16x16x32_bf16(
                                a0[rt], b, axn[g2][nt][rt], 0, 0, 0);
                    }
#pragma unroll
                    for (int t = 0; t < 4; ++t) {
                        bf16x8 b = *reinterpret_cast<const bf16x8*>(bq1 + t * 512);
#pragma unroll
                        for (int rt = 0; rt < 2; ++rt)
                            arz[g2][t][rt] = __builtin_amdgcn_mfma_f32_16x16x32_bf16(
                                a1[rt], b, arz[g2][t][rt], 0, 0, 0);
                    }
#pragma unroll
                    for (int nt = 0; nt < 2; ++nt) {
                        bf16x8 b = *reinterpret_cast<const bf16x8*>(bhp + nt * 512);
#pragma unroll
                        for (int rt = 0; rt < 2; ++rt)
                            ahn[g2][nt][rt] = __builtin_amdgcn_mfma_f32_16x16x32_bf16(
                                a1[rt], b, ahn[g2][nt][rt], 0, 0, 0);
                    }
                }
                bq00 += 4 * 512; bq01 += 4 * 512;
                bq10 += 4 * 512; bq11 += 4 * 512;
                bx0 += 2 * 512;  bx1 += 2 * 512;
                bh0 += 2 * 512;  bh1 += 2 * 512;
            }
            __syncthreads();  // B2: all h1 reads complete
#pragma unroll
            for (int g2 = 0; g2 < 2; ++g2)
#pragma unroll
                for (int nt = 0; nt < 2; ++nt) {
                    const int col = 32 * (2 * w + g2) + nt * 16 + lr;
#pragma unroll
                    for (int rt = 0; rt < 2; ++rt)
#pragma unroll
                        for (int rr = 0; rr < 4; ++rr) {
                            int row = rt * 16 + quad * 4 + rr;
                            float rg = fast_sigmoid(arz[g2][nt][rt][rr]);
                            float zg = fast_sigmoid(arz[g2][2 + nt][rt][rr]);
                            float ng = fast_tanh(axn[g2][nt][rt][rr] +
                                                 rg * ahn[g2][nt][rt][rr]);
                            float hold = bf2f(h1s[row * 264 + col]);
                            h1s[row * 264 + col] =
                                f2bf((1.f - zg) * ng + zg * hold);
                        }
                }
        }
        __syncthreads();  // B3: h1' visible

        // ---------------- delta = h1' @ ow.T + ob ; cumsum -> out
        {
            int brow = tid >> 3, p = tid & 7;   // 32 rows x 8 partials
            float d0 = 0.f, d1 = 0.f;
#pragma unroll
            for (int j = 0; j < 4; ++j) {
                int cb = ((p + brow) & 7) * 8 + j * 64;
                bf16x8 hv8 = *reinterpret_cast<const bf16x8*>(h1s + brow * 264 + cb);
#pragma unroll
                for (int i = 0; i < 8; ++i) {
                    float hv = bf2f(hv8[i]);
                    d0 += hv * owl[cb + i];
                    d1 += hv * owl[256 + cb + i];
                }
            }
            d0 += __shfl_xor(d0, 1); d0 += __shfl_xor(d0, 2); d0 += __shfl_xor(d0, 4);
            d1 += __shfl_xor(d1, 1); d1 += __shfl_xor(d1, 2); d1 += __shfl_xor(d1, 4);
            d0 += ob0v;
            d1 += ob1v;
            if (p == 0) {
                cum0 += d0;
                cum1 += d1;
                size_t o = (((size_t)(b0 + brow) * 3 + m) * (size_t)T + st) * 2;
                out[o] = cum0;
                out[o + 1] = cum1;
                posD[brow * 2] = d0;
                posD[brow * 2 + 1] = d1;
            }
        }
        __syncthreads();  // B4: posD ready
    }
}

// ---------------------------------------------------------------------------
// decoder_base: verbatim R14 (proven 894us). Fallback when ws_size too small.
// ---------------------------------------------------------------------------
__global__ __launch_bounds__(512, 2) void decoder_base(
    const float* __restrict__ context,
    const float* __restrict__ w_ih0_f,
    const float* __restrict__ b_ih0, const float* __restrict__ b_hh0,
    const float* __restrict__ b_ih1, const float* __restrict__ b_hh1,
    const float* __restrict__ out_w, const float* __restrict__ out_b,
    const short* __restrict__ ws, float* __restrict__ out,
    const int* __restrict__ pT, int ntiles) {
    __shared__ short ctxS[64 * 264];
    __shared__ short h0a[64 * 264], h0b[64 * 264];
    __shared__ short h1s[64 * 264];
    __shared__ float posD[128];
    __shared__ float owl[512];
    __shared__ float cwp0[768], cwp1[768];
    __shared__ float cbA[512];
    __shared__ float cbXn[256];
    __shared__ float cbh0n[256];
    __shared__ float cb1A[512];
    __shared__ float cb1X[256];
    __shared__ float cb1H[256];

    const int bid = blockIdx.x;
    const int xcd = bid & 7, slot = bid >> 3;
    int mode, xl, nx;
    if (xcd < 3)      { mode = 0; xl = xcd;     nx = 3; }
    else if (xcd < 6) { mode = 1; xl = xcd - 3; nx = 3; }
    else              { mode = 2; xl = xcd - 6; nx = 2; }
    const int g = slot * nx + xl;
    if (g >= ntiles) return;
    const int m = mode;
    const int b0 = g * 64;

    const int T = *pT;
    const int tid = threadIdx.x;
    const int lane = tid & 63, w = tid >> 6;
    const int lr = lane & 15, quad = lane >> 4;

    if (tid < 128) posD[tid] = 0.f;
    owl[tid] = out_w[m * 512 + tid];
    if (tid < 512) {
        cbA[tid] = b_ih0[m * 768 + tid] + b_hh0[m * 768 + tid];
        cb1A[tid] = b_ih1[m * 768 + tid] + b_hh1[m * 768 + tid];
    }
    if (tid < 256) {
        cbXn[tid] = b_ih0[m * 768 + 512 + tid];
        cbh0n[tid] = b_hh0[m * 768 + 512 + tid];
        cb1X[tid] = b_ih1[m * 768 + 512 + tid];
        cb1H[tid] = b_hh1[m * 768 + 512 + tid];
    }
    for (int c = tid; c < 768; c += 512) {
        cwp0[c] = w_ih0_f[((size_t)m * 768 + c) * 258 + 0];
        cwp1[c] = w_ih0_f[((size_t)m * 768 + c) * 258 + 1];
    }
#pragma unroll
    for (int i = 0; i < 32; ++i) {
        int idx = tid + i * 512;
        int r = idx >> 8, k = idx & 255;
        short v = f2bf(context[(size_t)(b0 + r) * 256 + k]);
        ctxS[r * 264 + k] = v;
        h0a[r * 264 + k] = v;
        h1s[r * 264 + k] = v;
    }
    const float ob0v = out_b[m * 2 + 0], ob1v = out_b[m * 2 + 1];

    const short* p0w = ws + ((size_t)(m * 8 + w) * 48) * 512 + lane * 8;
    const short* p1w = ws + (size_t)1152 * 512 + ((size_t)(m * 8 + w) * 96) * 512 + lane * 8;
    const short* pcw = ws + (size_t)3456 * 512 + ((size_t)(m * 8 + w) * 48) * 512 + lane * 8;

    const int cA = 32 * w + lr;
    const int cB = 32 * w + 16 + lr;

    __syncthreads();

    float cum0 = 0.f, cum1 = 0.f;

    for (int st = 0; st < T; ++st) {
        const short* h0c = (st & 1) ? h0b : h0a;
        short* h0n_ = (st & 1) ? h0a : h0b;

        {
            f32x4 arz[4][4], axn[2][4], ahn[2][4];
#pragma unroll
            for (int rt = 0; rt < 4; ++rt)
#pragma unroll
                for (int r = 0; r < 4; ++r) {
                    int row = rt * 16 + quad * 4 + r;
                    float px = posD[row * 2], py = posD[row * 2 + 1];
#pragma unroll
                    for (int t = 0; t < 4; ++t) {
                        int c = (t >> 1) * 256 + ((t & 1) ? cB : cA);
                        arz[t][rt][r] = cbA[c] + px * cwp0[c] + py * cwp1[c];
                    }
#pragma unroll
                    for (int nt = 0; nt < 2; ++nt) {
                        int cn = nt ? cB : cA;
                        axn[nt][rt][r] = cbXn[cn] + px * cwp0[512 + cn] +
                                         py * cwp1[512 + cn];
                        ahn[nt][rt][r] = cbh0n[cn];
                    }
                }
            const short* bpc = pcw;
            const short* bp0rz = p0w;
            const short* bp0n = p0w + 32 * 512;
#pragma unroll 1
            for (int ks = 0; ks < 8; ++ks) {
                bf16x8 ac[4], ah[4];
#pragma unroll
                for (int rt = 0; rt < 4; ++rt) {
                    ac[rt] = *reinterpret_cast<const bf16x8*>(
                        ctxS + (rt * 16 + lr) * 264 + ks * 32 + quad * 8);
                    ah[rt] = *reinterpret_cast<const bf16x8*>(
                        h0c + (rt * 16 + lr) * 264 + ks * 32 + quad * 8);
                }
#pragma unroll
                for (int t = 0; t < 4; ++t) {
                    bf16x8 b = *reinterpret_cast<const bf16x8*>(bpc + t * 512);
#pragma unroll
                    for (int rt = 0; rt < 4; ++rt)
                        arz[t][rt] = __builtin_amdgcn_mfma_f32_16x16x32_bf16(
                            ac[rt], b, arz[t][rt], 0, 0, 0);
                }
#pragma unroll
                for (int nt = 0; nt < 2; ++nt) {
                    bf16x8 b = *reinterpret_cast<const bf16x8*>(bpc + (4 + nt) * 512);
#pragma unroll
                    for (int rt = 0; rt < 4; ++rt)
                        axn[nt][rt] = __builtin_amdgcn_mfma_f32_16x16x32_bf16(
                            ac[rt], b, axn[nt][rt], 0, 0, 0);
                }
#pragma unroll
                for (int t = 0; t < 4; ++t) {
                    bf16x8 b = *reinterpret_cast<const bf16x8*>(bp0rz + t * 512);
#pragma unroll
                    for (int rt = 0; rt < 4; ++rt)
                        arz[t][rt] = __builtin_amdgcn_mfma_f32_16x16x32_bf16(
                            ah[rt], b, arz[t][rt], 0, 0, 0);
                }
#pragma unroll
                for (int nt = 0; nt < 2; ++nt) {
                    bf16x8 b = *reinterpret_cast<const bf16x8*>(bp0n + nt * 512);
#pragma unroll
                    for (int rt = 0; rt < 4; ++rt)
                        ahn[nt][rt] = __builtin_amdgcn_mfma_f32_16x16x32_bf16(
                            ah[rt], b, ahn[nt][rt], 0, 0, 0);
                }
                bpc += 6 * 512;
                bp0rz += 4 * 512;
                bp0n += 2 * 512;
            }
#pragma unroll
            for (int nt = 0; nt < 2; ++nt) {
                int col = nt ? cB : cA;
#pragma unroll
                for (int rt = 0; rt < 4; ++rt)
#pragma unroll
                    for (int r = 0; r < 4; ++r) {
                        int row = rt * 16 + quad * 4 + r;
                        float rr = fast_sigmoid(arz[nt][rt][r]);
                        float zz = fast_sigmoid(arz[2 + nt][rt][r]);
                        float nn =
                            fast_tanh(axn[nt][rt][r] + rr * ahn[nt][rt][r]);
                        float hold = bf2f(h0c[row * 264 + col]);
                        h0n_[row * 264 + col] = f2bf((1.f - zz) * nn + zz * hold);
                    }
            }
        }
        __syncthreads();

        {
            f32x4 arz[4][4], axn[2][4], ahn[2][4];
#pragma unroll
            for (int rt = 0; rt < 4; ++rt)
#pragma unroll
                for (int r = 0; r < 4; ++r) {
#pragma unroll
                    for (int t = 0; t < 4; ++t) {
                        int c = (t >> 1) * 256 + ((t & 1) ? cB : cA);
                        arz[t][rt][r] = cb1A[c];
                    }
#pragma unroll
                    for (int nt = 0; nt < 2; ++nt) {
                        int cn = nt ? cB : cA;
                        axn[nt][rt][r] = cb1X[cn];
                        ahn[nt][rt][r] = cb1H[cn];
                    }
                }
            const short* bq0 = p1w;
            const short* bq1 = p1w + 32 * 512;
            const short* bx = p1w + 64 * 512;
            const short* bh = p1w + 80 * 512;
#pragma unroll 1
            for (int ks = 0; ks < 8; ++ks) {
                bf16x8 a0[4], a1[4];
#pragma unroll
                for (int rt = 0; rt < 4; ++rt) {
                    a0[rt] = *reinterpret_cast<const bf16x8*>(
                        h0n_ + (rt * 16 + lr) * 264 + ks * 32 + quad * 8);
                    a1[rt] = *reinterpret_cast<const bf16x8*>(
                        h1s + (rt * 16 + lr) * 264 + ks * 32 + quad * 8);
                }
#pragma unroll
                for (int t = 0; t < 4; ++t) {
                    bf16x8 b = *reinterpret_cast<const bf16x8*>(bq0 + t * 512);
#pragma unroll
                    for (int rt = 0; rt < 4; ++rt)
                        arz[t][rt] = __builtin_amdgcn_mfma_f32_16x16x32_bf16(
                            a0[rt], b, arz[t][rt], 0, 0, 0);
                }
#pragma unroll
                for (int nt = 0; nt < 2; ++nt) {
                    bf16x8 b = *reinterpret_cast<const bf16x8*>(bx + nt * 512);
#pragma unroll
                    for (int rt = 0; rt < 4; ++rt)
                        axn[nt][rt] = __builtin_amdgcn_mfma_f32_16x16x32_bf16(
                            a0[rt], b, axn[nt][rt], 0, 0, 0);
                }
#pragma unroll
                for (int t = 0; t < 4; ++t) {
                    bf16x8 b = *reinterpret_cast<const bf16x8*>(bq1 + t * 512);
#pragma unroll
                    for (int rt = 0; rt < 4; ++rt)
                        arz[t][rt] = __builtin_amdgcn_mfma_f32_16x16x32_bf16(
                            a1[rt], b, arz[t][rt], 0, 0, 0);
                }
#pragma unroll
                for (int nt = 0; nt < 2; ++nt) {
                    bf16x8 b = *reinterpret_cast<const bf16x8*>(bh + nt * 512);
#pragma unroll
                    for (int rt = 0; rt < 4; ++rt)
                        ahn[nt][rt] = __builtin_amdgcn_mfma_f32_16x16x32_bf16(
                            a1[rt], b, ahn[nt][rt], 0, 0, 0);
                }
                bq0 += 4 * 512;
                bq1 += 4 * 512;
                bx += 2 * 512;
                bh += 2 * 512;
            }
            __syncthreads();
#pragma unroll
            for (int nt = 0; nt < 2; ++nt) {
                int col = nt ? cB : cA;
#pragma unroll
                for (int rt = 0; rt < 4; ++rt)
#pragma unroll
                    for (int r = 0; r < 4; ++r) {
                        int row = rt * 16 + quad * 4 + r;
                        float rr = fast_sigmoid(arz[nt][rt][r]);
                        float zz = fast_sigmoid(arz[2 + nt][rt][r]);
                        float nn =
                            fast_tanh(axn[nt][rt][r] + rr * ahn[nt][rt][r]);
                        float hold = bf2f(h1s[row * 264 + col]);
                        h1s[row * 264 + col] = f2bf((1.f - zz) * nn + zz * hold);
                    }
            }
        }
        __syncthreads();

        {
            int brow = tid >> 3, p = tid & 7;
            float d0 = 0.f, d1 = 0.f;
#pragma unroll
            for (int j = 0; j < 4; ++j) {
                int cb = ((p + brow) & 7) * 8 + j * 64;
                bf16x8 hv8 = *reinterpret_cast<const bf16x8*>(h1s + brow * 264 + cb);
#pragma unroll
                for (int i = 0; i < 8; ++i) {
                    float hv = bf2f(hv8[i]);
                    d0 += hv * owl[cb + i];
                    d1 += hv * owl[256 + cb + i];
                }
            }
            d0 += __shfl_xor(d0, 1); d0 += __shfl_xor(d0, 2); d0 += __shfl_xor(d0, 4);
            d1 += __shfl_xor(d1, 1); d1 += __shfl_xor(d1, 2); d1 += __shfl_xor(d1, 4);
            d0 += ob0v;
            d1 += ob1v;
            if (p == 0) {
                cum0 += d0;
                cum1 += d1;
                size_t o = (((size_t)(b0 + brow) * 3 + m) * (size_t)T + st) * 2;
                out[o] = cum0;
                out[o + 1] = cum1;
                posD[brow * 2] = d0;
                posD[brow * 2 + 1] = d1;
            }
        }
        __syncthreads();
    }
}

extern "C" void kernel_launch(void* const* d_in, const int* in_sizes, int n_in,
                              void* d_out, int out_size, void* d_ws, size_t ws_size,
                              hipStream_t stream) {
    const float* context = (const float*)d_in[0];
    const float* mp_w1 = (const float*)d_in[1];
    const float* mp_b1 = (const float*)d_in[2];
    const float* mp_w2 = (const float*)d_in[3];
    const float* mp_b2 = (const float*)d_in[4];
    const float* w_ih0 = (const float*)d_in[5];
    const float* w_hh0 = (const float*)d_in[6];
    const float* b_ih0 = (const float*)d_in[7];
    const float* b_hh0 = (const float*)d_in[8];
    const float* w_ih1 = (const float*)d_in[9];
    const float* w_hh1 = (const float*)d_in[10];
    const float* b_ih1 = (const float*)d_in[11];
    const float* b_hh1 = (const float*)d_in[12];
    const float* out_w = (const float*)d_in[13];
    const float* out_b = (const float*)d_in[14];
    const int* pT = (const int*)d_in[15];
    float* out = (float*)d_out;
    short* ws = (short*)d_ws;

    const int B = in_sizes[0] / 256;                      // 4096
    const long probs_off = (long)out_size - (long)B * 3;

    prep_kernel<<<4608, 64, 0, stream>>>(w_ih0, w_hh0, w_ih1, w_hh1, ws);
    modeprobs_kernel<<<B / 64, 256, 0, stream>>>(context, mp_w1, mp_b1, mp_w2,
                                                 mp_b2, out, probs_off);

    // gxc_xn cache: prep region + nwork blocks * 8 groups * 4 frags * 256
    // shorts. Guard against OOB ws writes.
    const int tilesPerMode = B / 32;                      // 128
    const int nwork = 3 * tilesPerMode;                   // 384
    const size_t needed =
        ((size_t)4608 * 512 + (size_t)nwork * 8 * 4 * 256) * sizeof(short);
    if (ws_size >= needed) {
        const int grid = 8 * ((nwork + 7) / 8);           // 384
        decoder_gxc32<<<grid, 256, 0, stream>>>(
            context, w_ih0, b_ih0, b_hh0, b_ih1, b_hh1, out_w, out_b, ws, out,
            pT, tilesPerMode, nwork);
    } else {
        const int ntiles = B / 64;
        const int nslots = (ntiles + 1) / 2;
        decoder_base<<<8 * nslots, 512, 0, stream>>>(
            context, w_ih0, b_ih0, b_hh0, b_ih1, b_hh1, out_w, out_b, ws, out,
            pT, ntiles);
    }
}

// Round 11
// 871.735 us; speedup vs baseline: 1.1504x; 1.1504x over previous
//
#include <hip/hip_runtime.h>

// ---------------------------------------------------------------------------
// TrajectoryDecoder: B=4096, F=256, H=256, M=3, T=30 (T read from device)
// out = [trajectories (B,M,T,2) fp32][mode_probs (B,M) fp32]
// R25 = R23 (best: 791us decoder) + two zero-resource trims:
//  (1) raw barriers (lgkmcnt-only) for the 5 in-step barriers -- skip the
//      vmcnt drain; xn loads / out stores ride through (their consumers have
//      compiler-inserted waits). LDS hazards fully ordered by lgkmcnt(0).
//  (2) s_setprio(1) around MFMA K-loops (T5): when one wave of a SIMD is in
//      epilogue/init (prio 0) and the other in its K-loop, the MFMA wave
//      wins issue arbitration.
// R24 (2 blocks/CU post-gxc) measured +12%: de-correlation ALWAYS duplicates
// the per-CU weight stream (1.18MB/step x domains) -- line closed. R23
// structure kept verbatim otherwise: gxc_rz in LDS, gxc_xn in global L2,
// single h0, 64-row x 8-wave blocks. ws guard + R14 fallback kept.
// ---------------------------------------------------------------------------

typedef __attribute__((ext_vector_type(8))) short bf16x8;
typedef __attribute__((ext_vector_type(4))) short short4n;
typedef __attribute__((ext_vector_type(4))) float f32x4;

__device__ __forceinline__ short f2bf(float f) {
    unsigned u = __builtin_bit_cast(unsigned, f);
    unsigned r = (u + 0x7fffu + ((u >> 16) & 1u)) >> 16;
    return (short)r;
}
__device__ __forceinline__ float bf2f(short s) {
    unsigned u = ((unsigned)(unsigned short)s) << 16;
    return __builtin_bit_cast(float, u);
}
__device__ __forceinline__ float fast_sigmoid(float x) {
    x = fminf(fmaxf(x, -30.f), 30.f);
    float e = __builtin_amdgcn_exp2f(x * -1.442695041f);
    return __builtin_amdgcn_rcpf(1.f + e);
}
__device__ __forceinline__ float fast_tanh(float x) {
    x = fminf(fmaxf(x, -15.f), 15.f);
    float e = __builtin_amdgcn_exp2f(x * -2.885390082f);
    return (1.f - e) * __builtin_amdgcn_rcpf(1.f + e);
}
__device__ __forceinline__ void barrier_fast() {
    // LDS-only barrier: drain DS ops, skip vmcnt/expcnt drain.
    asm volatile("s_waitcnt lgkmcnt(0)" ::: "memory");
    __builtin_amdgcn_s_barrier();
}

// ---------------------------------------------------------------------------
// Weight prep: fp32 -> bf16, B-fragment consumption order (R14 layout).
//   P0  [0,1152):    w_hh0 per (m,w8): 48 = [rz: ks*4+t (32)][n: 32+ks*2+nt]
//   P1  [1152,3456): per (m,w8): 96 = [rz: half*32+ks*4+t (64)]
//                                     [xn: 64+ks*2+nt][hn: 80+ks*2+nt]
//   PC  [3456,4608): w_ih0[:,2:258] per (m,w8): 48 = [ks*6+t6]
// gxc_xn region (decoder prologue): [4608*512, +3*ntiles*8*8*256) shorts
// ---------------------------------------------------------------------------
__global__ void prep_kernel(const float* __restrict__ w_ih0,
                            const float* __restrict__ w_hh0,
                            const float* __restrict__ w_ih1,
                            const float* __restrict__ w_hh1,
                            short* __restrict__ ws) {
    int bid = blockIdx.x;
    int L = threadIdx.x;
    const float* src;
    int srcRowLen, colBase, m, w, ks, t;
    if (bid < 1152) {
        int idx = bid, mw = idx / 48, blk = idx % 48;
        m = mw / 8; w = mw % 8;
        if (blk < 32) { ks = blk >> 2; t = blk & 3; }
        else { int q = blk - 32; ks = q >> 1; t = 4 + (q & 1); }
        src = w_hh0 + (size_t)m * 768 * 256; srcRowLen = 256; colBase = 0;
    } else if (bid < 3456) {
        int idx = bid - 1152, mw = idx / 96, blk = idx % 96;
        m = mw / 8; w = mw % 8;
        int half;
        if (blk < 64) { half = blk >> 5; ks = (blk >> 2) & 7; t = blk & 3; }
        else { int q = blk - 64; half = q >> 4; ks = (q >> 1) & 7; t = 4 + (q & 1); }
        src = (half ? w_hh1 : w_ih1) + (size_t)m * 768 * 256;
        srcRowLen = 256; colBase = 0;
    } else {
        int idx = bid - 3456, mw = idx / 48, blk = idx % 48;
        m = mw / 8; w = mw % 8; ks = blk / 6; t = blk % 6;
        src = w_ih0 + (size_t)m * 768 * 258; srcRowLen = 258; colBase = 2;
    }
    int row = (t >> 1) * 256 + 32 * w + (t & 1) * 16 + (L & 15);
    int col0 = colBase + ks * 32 + (L >> 4) * 8;
    short* dst = ws + (size_t)bid * 512 + L * 8;
    const float* s = src + (size_t)row * srcRowLen + col0;
#pragma unroll
    for (int j = 0; j < 8; ++j) dst[j] = f2bf(s[j]);
}

// ---------------------------------------------------------------------------
// Mode-probability MLP
// ---------------------------------------------------------------------------
__global__ __launch_bounds__(256) void modeprobs_kernel(
    const float* __restrict__ ctx, const float* __restrict__ w1,
    const float* __restrict__ b1, const float* __restrict__ w2,
    const float* __restrict__ b2, float* __restrict__ out,
    long probs_off) {
    __shared__ float w1s[64 * 256];
    int tid = threadIdx.x;
    int j = tid & 63;
    int rsub = tid >> 6;
#pragma unroll
    for (int i = 0; i < 64; ++i) w1s[tid + i * 256] = w1[tid + i * 256];
    float b1v = b1[j];
    float w2v0 = w2[j], w2v1 = w2[64 + j], w2v2 = w2[128 + j];
    float b20 = b2[0], b21 = b2[1], b22 = b2[2];
    __syncthreads();
    for (int c = 0; c < 16; ++c) {
        int brow = blockIdx.x * 64 + c * 4 + rsub;
        const float* crow = ctx + (size_t)brow * 256;
        float accv = b1v;
#pragma unroll 8
        for (int k = 0; k < 256; ++k) {
            int kk = (k + j) & 255;
            accv += w1s[j * 256 + kk] * crow[kk];
        }
        float h = fmaxf(accv, 0.f);
        float l0 = h * w2v0, l1 = h * w2v1, l2 = h * w2v2;
#pragma unroll
        for (int s = 1; s < 64; s <<= 1) {
            l0 += __shfl_xor(l0, s);
            l1 += __shfl_xor(l1, s);
            l2 += __shfl_xor(l2, s);
        }
        if (j == 0) {
            l0 += b20; l1 += b21; l2 += b22;
            float mx = fmaxf(l0, fmaxf(l1, l2));
            float e0 = __builtin_amdgcn_exp2f((l0 - mx) * 1.442695041f);
            float e1 = __builtin_amdgcn_exp2f((l1 - mx) * 1.442695041f);
            float e2 = __builtin_amdgcn_exp2f((l2 - mx) * 1.442695041f);
            float inv = 1.f / (e0 + e1 + e2);
            out[probs_off + (size_t)brow * 3 + 0] = e0 * inv;
            out[probs_off + (size_t)brow * 3 + 1] = e1 * inv;
            out[probs_off + (size_t)brow * 3 + 2] = e2 * inv;
        }
    }
}

// ---------------------------------------------------------------------------
// decoder_gxc2: 64-row x 8-wave block, single h0, gxc_rz in LDS, gxc_xn in
// global (L2-resident). 5 raw barriers/step, setprio around MFMA loops.
// ---------------------------------------------------------------------------
__global__ __launch_bounds__(512, 2) void decoder_gxc2(
    const float* __restrict__ context,
    const float* __restrict__ w_ih0_f,
    const float* __restrict__ b_ih0, const float* __restrict__ b_hh0,
    const float* __restrict__ b_ih1, const float* __restrict__ b_hh1,
    const float* __restrict__ out_w, const float* __restrict__ out_b,
    short* ws, float* __restrict__ out,
    const int* __restrict__ pT, int ntiles) {
    __shared__ short h0s[64 * 264];           // single h0 (in-place update)
    __shared__ short h1s[64 * 264];
    __shared__ short gxcrz[8 * 16 * 256];     // [w][t*4+rt][lane*4..+3] bf16
    __shared__ float posD[128];
    __shared__ float owl[512];
    __shared__ short cwp0h[768], cwp1h[768];  // pos weights (bf16)
    __shared__ float cbA[512];                // prologue: b_ih0+b_hh0 (rz)
    __shared__ float cbXn[256];               // prologue: b_ih0 (n)
    __shared__ float cbh0n[256];              // per-step ahn init
    __shared__ float cb1A[512];
    __shared__ float cb1X[256];
    __shared__ float cb1H[256];

    const int bid = blockIdx.x;
    const int xcd = bid & 7, slot = bid >> 3;
    int mode, xl, nx;
    if (xcd < 3)      { mode = 0; xl = xcd;     nx = 3; }
    else if (xcd < 6) { mode = 1; xl = xcd - 3; nx = 3; }
    else              { mode = 2; xl = xcd - 6; nx = 2; }
    const int g = slot * nx + xl;
    if (g >= ntiles) return;
    const int m = mode;
    const int b0 = g * 64;
    const int wk = m * ntiles + g;

    const int T = *pT;
    const int tid = threadIdx.x;
    const int lane = tid & 63, w = tid >> 6;
    const int lr = lane & 15, quad = lane >> 4;

    if (tid < 128) posD[tid] = 0.f;
    owl[tid] = out_w[m * 512 + tid];
    if (tid < 512) {
        cbA[tid] = b_ih0[m * 768 + tid] + b_hh0[m * 768 + tid];
        cb1A[tid] = b_ih1[m * 768 + tid] + b_hh1[m * 768 + tid];
    }
    if (tid < 256) {
        cbXn[tid] = b_ih0[m * 768 + 512 + tid];
        cbh0n[tid] = b_hh0[m * 768 + 512 + tid];
        cb1X[tid] = b_ih1[m * 768 + 512 + tid];
        cb1H[tid] = b_hh1[m * 768 + 512 + tid];
    }
    for (int cc = tid; cc < 768; cc += 512) {
        cwp0h[cc] = f2bf(w_ih0_f[((size_t)m * 768 + cc) * 258 + 0]);
        cwp1h[cc] = f2bf(w_ih0_f[((size_t)m * 768 + cc) * 258 + 1]);
    }
#pragma unroll
    for (int i = 0; i < 32; ++i) {
        int idx = tid + i * 512;
        int r = idx >> 8, k = idx & 255;
        short v = f2bf(context[(size_t)(b0 + r) * 256 + k]);
        h0s[r * 264 + k] = v;   // h0 init = ctx; also prologue A-source
        h1s[r * 264 + k] = v;
    }
    const float ob0v = out_b[m * 2 + 0], ob1v = out_b[m * 2 + 1];

    const short* p0w = ws + ((size_t)(m * 8 + w) * 48) * 512 + lane * 8;
    const short* p1w = ws + (size_t)1152 * 512 + ((size_t)(m * 8 + w) * 96) * 512 + lane * 8;
    const short* pcw = ws + (size_t)3456 * 512 + ((size_t)(m * 8 + w) * 48) * 512 + lane * 8;

    // global xn-fragment cache: [(wk*8+w)*8 + tile][lane][4] bf16
    short* gxw = ws + (size_t)4608 * 512 +
                 ((size_t)(wk * 8 + w) * 8) * 256 + lane * 4;
    // per-wave LDS rz-fragment base
    short* grz = gxcrz + (w * 16) * 256 + lane * 4;

    const int cA = 32 * w + lr;
    const int cB = 32 * w + 16 + lr;

    __syncthreads();

    // ======== prologue: gxc = bias + ctx @ w_ih0[:,2:]^T (once) ========
    {
        f32x4 arz[4][4], axn[2][4];
#pragma unroll
        for (int rt = 0; rt < 4; ++rt)
#pragma unroll
            for (int r = 0; r < 4; ++r) {
#pragma unroll
                for (int t = 0; t < 4; ++t) {
                    int c = (t >> 1) * 256 + ((t & 1) ? cB : cA);
                    arz[t][rt][r] = cbA[c];
                }
#pragma unroll
                for (int nt = 0; nt < 2; ++nt)
                    axn[nt][rt][r] = cbXn[nt ? cB : cA];
            }
        const short* bpc = pcw;
        __builtin_amdgcn_s_setprio(1);
#pragma unroll 1
        for (int ks = 0; ks < 8; ++ks) {
            bf16x8 ac[4];
#pragma unroll
            for (int rt = 0; rt < 4; ++rt)
                ac[rt] = *reinterpret_cast<const bf16x8*>(
                    h0s + (rt * 16 + lr) * 264 + ks * 32 + quad * 8);
#pragma unroll
            for (int t = 0; t < 4; ++t) {
                bf16x8 b = *reinterpret_cast<const bf16x8*>(bpc + t * 512);
#pragma unroll
                for (int rt = 0; rt < 4; ++rt)
                    arz[t][rt] = __builtin_amdgcn_mfma_f32_16x16x32_bf16(
                        ac[rt], b, arz[t][rt], 0, 0, 0);
            }
#pragma unroll
            for (int nt = 0; nt < 2; ++nt) {
                bf16x8 b = *reinterpret_cast<const bf16x8*>(bpc + (4 + nt) * 512);
#pragma unroll
                for (int rt = 0; rt < 4; ++rt)
                    axn[nt][rt] = __builtin_amdgcn_mfma_f32_16x16x32_bf16(
                        ac[rt], b, axn[nt][rt], 0, 0, 0);
            }
            bpc += 6 * 512;
        }
        __builtin_amdgcn_s_setprio(0);
        // rz fragments -> LDS (per-wave private region)
#pragma unroll
        for (int t = 0; t < 4; ++t)
#pragma unroll
            for (int rt = 0; rt < 4; ++rt) {
                short4n pk;
#pragma unroll
                for (int r = 0; r < 4; ++r) pk[r] = f2bf(arz[t][rt][r]);
                *reinterpret_cast<short4n*>(grz + (t * 4 + rt) * 256) = pk;
            }
        // xn fragments -> global (per-wave private region)
#pragma unroll
        for (int nt = 0; nt < 2; ++nt)
#pragma unroll
            for (int rt = 0; rt < 4; ++rt) {
                short4n pk;
#pragma unroll
                for (int r = 0; r < 4; ++r) pk[r] = f2bf(axn[nt][rt][r]);
                *reinterpret_cast<short4n*>(gxw + (nt * 4 + rt) * 256) = pk;
            }
        asm volatile("s_waitcnt vmcnt(0)" ::: "memory");  // xn RAW safety
    }
    __syncthreads();

    float cum0 = 0.f, cum1 = 0.f;

    for (int st = 0; st < T; ++st) {
        // ======== layer 0: h-side only (x-part cached) ========
        {
            // opaque offset: keep the xn loads inside the step loop
            int gxo = 0;
            asm volatile("" : "+v"(gxo));
            const short* gq = gxw + gxo;

            f32x4 arz[4][4], axn[2][4], ahn[2][4];
#pragma unroll
            for (int t = 0; t < 4; ++t) {
                const int c = (t >> 1) * 256 + ((t & 1) ? cB : cA);
                const float w0 = bf2f(cwp0h[c]), w1 = bf2f(cwp1h[c]);
#pragma unroll
                for (int rt = 0; rt < 4; ++rt) {
                    short4n v = *reinterpret_cast<const short4n*>(
                        grz + (t * 4 + rt) * 256);
#pragma unroll
                    for (int r = 0; r < 4; ++r) {
                        int row = rt * 16 + quad * 4 + r;
                        arz[t][rt][r] = bf2f(v[r]) + posD[row * 2] * w0 +
                                        posD[row * 2 + 1] * w1;
                    }
                }
            }
#pragma unroll
            for (int nt = 0; nt < 2; ++nt) {
                const int cn = nt ? cB : cA;
                const float w0 = bf2f(cwp0h[512 + cn]);
                const float w1 = bf2f(cwp1h[512 + cn]);
                const float bh = cbh0n[cn];
#pragma unroll
                for (int rt = 0; rt < 4; ++rt) {
                    short4n v = *reinterpret_cast<const short4n*>(
                        gq + (nt * 4 + rt) * 256);
#pragma unroll
                    for (int r = 0; r < 4; ++r) {
                        int row = rt * 16 + quad * 4 + r;
                        axn[nt][rt][r] = bf2f(v[r]) + posD[row * 2] * w0 +
                                         posD[row * 2 + 1] * w1;
                        ahn[nt][rt][r] = bh;
                    }
                }
            }
            const short* b0r = p0w;
            const short* b0n = p0w + 32 * 512;
            __builtin_amdgcn_s_setprio(1);
#pragma unroll 1
            for (int ks = 0; ks < 8; ++ks) {
                bf16x8 ah[4];
#pragma unroll
                for (int rt = 0; rt < 4; ++rt)
                    ah[rt] = *reinterpret_cast<const bf16x8*>(
                        h0s + (rt * 16 + lr) * 264 + ks * 32 + quad * 8);
#pragma unroll
                for (int t = 0; t < 4; ++t) {
                    bf16x8 b = *reinterpret_cast<const bf16x8*>(b0r + t * 512);
#pragma unroll
                    for (int rt = 0; rt < 4; ++rt)
                        arz[t][rt] = __builtin_amdgcn_mfma_f32_16x16x32_bf16(
                            ah[rt], b, arz[t][rt], 0, 0, 0);
                }
#pragma unroll
                for (int nt = 0; nt < 2; ++nt) {
                    bf16x8 b = *reinterpret_cast<const bf16x8*>(b0n + nt * 512);
#pragma unroll
                    for (int rt = 0; rt < 4; ++rt)
                        ahn[nt][rt] = __builtin_amdgcn_mfma_f32_16x16x32_bf16(
                            ah[rt], b, ahn[nt][rt], 0, 0, 0);
                }
                b0r += 4 * 512;
                b0n += 2 * 512;
            }
            __builtin_amdgcn_s_setprio(0);
            barrier_fast();  // B1a: all h0 reads complete (single buffer)
#pragma unroll
            for (int nt = 0; nt < 2; ++nt) {
                int col = nt ? cB : cA;
#pragma unroll
                for (int rt = 0; rt < 4; ++rt)
#pragma unroll
                    for (int r = 0; r < 4; ++r) {
                        int row = rt * 16 + quad * 4 + r;
                        float rr = fast_sigmoid(arz[nt][rt][r]);
                        float zz = fast_sigmoid(arz[2 + nt][rt][r]);
                        float nn =
                            fast_tanh(axn[nt][rt][r] + rr * ahn[nt][rt][r]);
                        float hold = bf2f(h0s[row * 264 + col]);
                        h0s[row * 264 + col] = f2bf((1.f - zz) * nn + zz * hold);
                    }
            }
        }
        barrier_fast();  // B1b: h0' visible

        // ======== layer 1 ========
        {
            f32x4 arz[4][4], axn[2][4], ahn[2][4];
#pragma unroll
            for (int rt = 0; rt < 4; ++rt)
#pragma unroll
                for (int r = 0; r < 4; ++r) {
#pragma unroll
                    for (int t = 0; t < 4; ++t) {
                        int c = (t >> 1) * 256 + ((t & 1) ? cB : cA);
                        arz[t][rt][r] = cb1A[c];
                    }
#pragma unroll
                    for (int nt = 0; nt < 2; ++nt) {
                        int cn = nt ? cB : cA;
                        axn[nt][rt][r] = cb1X[cn];
                        ahn[nt][rt][r] = cb1H[cn];
                    }
                }
            const short* bq0 = p1w;
            const short* bq1 = p1w + 32 * 512;
            const short* bx = p1w + 64 * 512;
            const short* bh = p1w + 80 * 512;
            __builtin_amdgcn_s_setprio(1);
#pragma unroll 1
            for (int ks = 0; ks < 8; ++ks) {
                bf16x8 a0[4], a1[4];
#pragma unroll
                for (int rt = 0; rt < 4; ++rt) {
                    a0[rt] = *reinterpret_cast<const bf16x8*>(
                        h0s + (rt * 16 + lr) * 264 + ks * 32 + quad * 8);
                    a1[rt] = *reinterpret_cast<const bf16x8*>(
                        h1s + (rt * 16 + lr) * 264 + ks * 32 + quad * 8);
                }
#pragma unroll
                for (int t = 0; t < 4; ++t) {
                    bf16x8 b = *reinterpret_cast<const bf16x8*>(bq0 + t * 512);
#pragma unroll
                    for (int rt = 0; rt < 4; ++rt)
                        arz[t][rt] = __builtin_amdgcn_mfma_f32_16x16x32_bf16(
                            a0[rt], b, arz[t][rt], 0, 0, 0);
                }
#pragma unroll
                for (int nt = 0; nt < 2; ++nt) {
                    bf16x8 b = *reinterpret_cast<const bf16x8*>(bx + nt * 512);
#pragma unroll
                    for (int rt = 0; rt < 4; ++rt)
                        axn[nt][rt] = __builtin_amdgcn_mfma_f32_16x16x32_bf16(
                            a0[rt], b, axn[nt][rt], 0, 0, 0);
                }
#pragma unroll
                for (int t = 0; t < 4; ++t) {
                    bf16x8 b = *reinterpret_cast<const bf16x8*>(bq1 + t * 512);
#pragma unroll
                    for (int rt = 0; rt < 4; ++rt)
                        arz[t][rt] = __builtin_amdgcn_mfma_f32_16x16x32_bf16(
                            a1[rt], b, arz[t][rt], 0, 0, 0);
                }
#pragma unroll
                for (int nt = 0; nt < 2; ++nt) {
                    bf16x8 b = *reinterpret_cast<const bf16x8*>(bh + nt * 512);
#pragma unroll
                    for (int rt = 0; rt < 4; ++rt)
                        ahn[nt][rt] = __builtin_amdgcn_mfma_f32_16x16x32_bf16(
                            a1[rt], b, ahn[nt][rt], 0, 0, 0);
                }
                bq0 += 4 * 512;
                bq1 += 4 * 512;
                bx += 2 * 512;
                bh += 2 * 512;
            }
            __builtin_amdgcn_s_setprio(0);
            barrier_fast();  // B2: all h1 reads complete
#pragma unroll
            for (int nt = 0; nt < 2; ++nt) {
                int col = nt ? cB : cA;
#pragma unroll
                for (int rt = 0; rt < 4; ++rt)
#pragma unroll
                    for (int r = 0; r < 4; ++r) {
                        int row = rt * 16 + quad * 4 + r;
                        float rr = fast_sigmoid(arz[nt][rt][r]);
                        float zz = fast_sigmoid(arz[2 + nt][rt][r]);
                        float nn =
                            fast_tanh(axn[nt][rt][r] + rr * ahn[nt][rt][r]);
                        float hold = bf2f(h1s[row * 264 + col]);
                        h1s[row * 264 + col] = f2bf((1.f - zz) * nn + zz * hold);
                    }
            }
        }
        barrier_fast();  // B3: h1' visible

        // ---------------- delta = h1' @ ow.T + ob ; cumsum -> out
        {
            int brow = tid >> 3, p = tid & 7;
            float d0 = 0.f, d1 = 0.f;
#pragma unroll
            for (int j = 0; j < 4; ++j) {
                int cb = ((p + brow) & 7) * 8 + j * 64;
                bf16x8 hv8 = *reinterpret_cast<const bf16x8*>(h1s + brow * 264 + cb);
#pragma unroll
                for (int i = 0; i < 8; ++i) {
                    float hv = bf2f(hv8[i]);
                    d0 += hv * owl[cb + i];
                    d1 += hv * owl[256 + cb + i];
                }
            }
            d0 += __shfl_xor(d0, 1); d0 += __shfl_xor(d0, 2); d0 += __shfl_xor(d0, 4);
            d1 += __shfl_xor(d1, 1); d1 += __shfl_xor(d1, 2); d1 += __shfl_xor(d1, 4);
            d0 += ob0v;
            d1 += ob1v;
            if (p == 0) {
                cum0 += d0;
                cum1 += d1;
                size_t o = (((size_t)(b0 + brow) * 3 + m) * (size_t)T + st) * 2;
                out[o] = cum0;
                out[o + 1] = cum1;
                posD[brow * 2] = d0;
                posD[brow * 2 + 1] = d1;
            }
        }
        barrier_fast();  // B4: posD ready
    }
}

// ---------------------------------------------------------------------------
// decoder_base: verbatim R14 (proven 894us). Fallback when ws_size too small.
// ---------------------------------------------------------------------------
__global__ __launch_bounds__(512, 2) void decoder_base(
    const float* __restrict__ context,
    const float* __restrict__ w_ih0_f,
    const float* __restrict__ b_ih0, const float* __restrict__ b_hh0,
    const float* __restrict__ b_ih1, const float* __restrict__ b_hh1,
    const float* __restrict__ out_w, const float* __restrict__ out_b,
    const short* __restrict__ ws, float* __restrict__ out,
    const int* __restrict__ pT, int ntiles) {
    __shared__ short ctxS[64 * 264];
    __shared__ short h0a[64 * 264], h0b[64 * 264];
    __shared__ short h1s[64 * 264];
    __shared__ float posD[128];
    __shared__ float owl[512];
    __shared__ float cwp0[768], cwp1[768];
    __shared__ float cbA[512];
    __shared__ float cbXn[256];
    __shared__ float cbh0n[256];
    __shared__ float cb1A[512];
    __shared__ float cb1X[256];
    __shared__ float cb1H[256];

    const int bid = blockIdx.x;
    const int xcd = bid & 7, slot = bid >> 3;
    int mode, xl, nx;
    if (xcd < 3)      { mode = 0; xl = xcd;     nx = 3; }
    else if (xcd < 6) { mode = 1; xl = xcd - 3; nx = 3; }
    else              { mode = 2; xl = xcd - 6; nx = 2; }
    const int g = slot * nx + xl;
    if (g >= ntiles) return;
    const int m = mode;
    const int b0 = g * 64;

    const int T = *pT;
    const int tid = threadIdx.x;
    const int lane = tid & 63, w = tid >> 6;
    const int lr = lane & 15, quad = lane >> 4;

    if (tid < 128) posD[tid] = 0.f;
    owl[tid] = out_w[m * 512 + tid];
    if (tid < 512) {
        cbA[tid] = b_ih0[m * 768 + tid] + b_hh0[m * 768 + tid];
        cb1A[tid] = b_ih1[m * 768 + tid] + b_hh1[m * 768 + tid];
    }
    if (tid < 256) {
        cbXn[tid] = b_ih0[m * 768 + 512 + tid];
        cbh0n[tid] = b_hh0[m * 768 + 512 + tid];
        cb1X[tid] = b_ih1[m * 768 + 512 + tid];
        cb1H[tid] = b_hh1[m * 768 + 512 + tid];
    }
    for (int c = tid; c < 768; c += 512) {
        cwp0[c] = w_ih0_f[((size_t)m * 768 + c) * 258 + 0];
        cwp1[c] = w_ih0_f[((size_t)m * 768 + c) * 258 + 1];
    }
#pragma unroll
    for (int i = 0; i < 32; ++i) {
        int idx = tid + i * 512;
        int r = idx >> 8, k = idx & 255;
        short v = f2bf(context[(size_t)(b0 + r) * 256 + k]);
        ctxS[r * 264 + k] = v;
        h0a[r * 264 + k] = v;
        h1s[r * 264 + k] = v;
    }
    const float ob0v = out_b[m * 2 + 0], ob1v = out_b[m * 2 + 1];

    const short* p0w = ws + ((size_t)(m * 8 + w) * 48) * 512 + lane * 8;
    const short* p1w = ws + (size_t)1152 * 512 + ((size_t)(m * 8 + w) * 96) * 512 + lane * 8;
    const short* pcw = ws + (size_t)3456 * 512 + ((size_t)(m * 8 + w) * 48) * 512 + lane * 8;

    const int cA = 32 * w + lr;
    const int cB = 32 * w + 16 + lr;

    __syncthreads();

    float cum0 = 0.f, cum1 = 0.f;

    for (int st = 0; st < T; ++st) {
        const short* h0c = (st & 1) ? h0b : h0a;
        short* h0n_ = (st & 1) ? h0a : h0b;

        {
            f32x4 arz[4][4], axn[2][4], ahn[2][4];
#pragma unroll
            for (int rt = 0; rt < 4; ++rt)
#pragma unroll
                for (int r = 0; r < 4; ++r) {
                    int row = rt * 16 + quad * 4 + r;
                    float px = posD[row * 2], py = posD[row * 2 + 1];
#pragma unroll
                    for (int t = 0; t < 4; ++t) {
                        int c = (t >> 1) * 256 + ((t & 1) ? cB : cA);
                        arz[t][rt][r] = cbA[c] + px * cwp0[c] + py * cwp1[c];
                    }
#pragma unroll
                    for (int nt = 0; nt < 2; ++nt) {
                        int cn = nt ? cB : cA;
                        axn[nt][rt][r] = cbXn[cn] + px * cwp0[512 + cn] +
                                         py * cwp1[512 + cn];
                        ahn[nt][rt][r] = cbh0n[cn];
                    }
                }
            const short* bpc = pcw;
            const short* bp0rz = p0w;
            const short* bp0n = p0w + 32 * 512;
#pragma unroll 1
            for (int ks = 0; ks < 8; ++ks) {
                bf16x8 ac[4], ah[4];
#pragma unroll
                for (int rt = 0; rt < 4; ++rt) {
                    ac[rt] = *reinterpret_cast<const bf16x8*>(
                        ctxS + (rt * 16 + lr) * 264 + ks * 32 + quad * 8);
                    ah[rt] = *reinterpret_cast<const bf16x8*>(
                        h0c + (rt * 16 + lr) * 264 + ks * 32 + quad * 8);
                }
#pragma unroll
                for (int t = 0; t < 4; ++t) {
                    bf16x8 b = *reinterpret_cast<const bf16x8*>(bpc + t * 512);
#pragma unroll
                    for (int rt = 0; rt < 4; ++rt)
                        arz[t][rt] = __builtin_amdgcn_mfma_f32_16x16x32_bf16(
                            ac[rt], b, arz[t][rt], 0, 0, 0);
                }
#pragma unroll
                for (int nt = 0; nt < 2; ++nt) {
                    bf16x8 b = *reinterpret_cast<const bf16x8*>(bpc + (4 + nt) * 512);
#pragma unroll
                    for (int rt = 0; rt < 4; ++rt)
                        axn[nt][rt] = __builtin_amdgcn_mfma_f32_16x16x32_bf16(
                            ac[rt], b, axn[nt][rt], 0, 0, 0);
                }
#pragma unroll
                for (int t = 0; t < 4; ++t) {
                    bf16x8 b = *reinterpret_cast<const bf16x8*>(bp0rz + t * 512);
#pragma unroll
                    for (int rt = 0; rt < 4; ++rt)
                        arz[t][rt] = __builtin_amdgcn_mfma_f32_16x16x32_bf16(
                            ah[rt], b, arz[t][rt], 0, 0, 0);
                }
#pragma unroll
                for (int nt = 0; nt < 2; ++nt) {
                    bf16x8 b = *reinterpret_cast<const bf16x8*>(bp0n + nt * 512);
#pragma unroll
                    for (int rt = 0; rt < 4; ++rt)
                        ahn[nt][rt] = __builtin_amdgcn_mfma_f32_16x16x32_bf16(
                            ah[rt], b, ahn[nt][rt], 0, 0, 0);
                }
                bpc += 6 * 512;
                bp0rz += 4 * 512;
                bp0n += 2 * 512;
            }
#pragma unroll
            for (int nt = 0; nt < 2; ++nt) {
                int col = nt ? cB : cA;
#pragma unroll
                for (int rt = 0; rt < 4; ++rt)
#pragma unroll
                    for (int r = 0; r < 4; ++r) {
                        int row = rt * 16 + quad * 4 + r;
                        float rr = fast_sigmoid(arz[nt][rt][r]);
                        float zz = fast_sigmoid(arz[2 + nt][rt][r]);
                        float nn =
                            fast_tanh(axn[nt][rt][r] + rr * ahn[nt][rt][r]);
                        float hold = bf2f(h0c[row * 264 + col]);
                        h0n_[row * 264 + col] = f2bf((1.f - zz) * nn + zz * hold);
                    }
            }
        }
        __syncthreads();

        {
            f32x4 arz[4][4], axn[2][4], ahn[2][4];
#pragma unroll
            for (int rt = 0; rt < 4; ++rt)
#pragma unroll
                for (int r = 0; r < 4; ++r) {
#pragma unroll
                    for (int t = 0; t < 4; ++t) {
                        int c = (t >> 1) * 256 + ((t & 1) ? cB : cA);
                        arz[t][rt][r] = cb1A[c];
                    }
#pragma unroll
                    for (int nt = 0; nt < 2; ++nt) {
                        int cn = nt ? cB : cA;
                        axn[nt][rt][r] = cb1X[cn];
                        ahn[nt][rt][r] = cb1H[cn];
                    }
                }
            const short* bq0 = p1w;
            const short* bq1 = p1w + 32 * 512;
            const short* bx = p1w + 64 * 512;
            const short* bh = p1w + 80 * 512;
#pragma unroll 1
            for (int ks = 0; ks < 8; ++ks) {
                bf16x8 a0[4], a1[4];
#pragma unroll
                for (int rt = 0; rt < 4; ++rt) {
                    a0[rt] = *reinterpret_cast<const bf16x8*>(
                        h0n_ + (rt * 16 + lr) * 264 + ks * 32 + quad * 8);
                    a1[rt] = *reinterpret_cast<const bf16x8*>(
                        h1s + (rt * 16 + lr) * 264 + ks * 32 + quad * 8);
                }
#pragma unroll
                for (int t = 0; t < 4; ++t) {
                    bf16x8 b = *reinterpret_cast<const bf16x8*>(bq0 + t * 512);
#pragma unroll
                    for (int rt = 0; rt < 4; ++rt)
                        arz[t][rt] = __builtin_amdgcn_mfma_f32_16x16x32_bf16(
                            a0[rt], b, arz[t][rt], 0, 0, 0);
                }
#pragma unroll
                for (int nt = 0; nt < 2; ++nt) {
                    bf16x8 b = *reinterpret_cast<const bf16x8*>(bx + nt * 512);
#pragma unroll
                    for (int rt = 0; rt < 4; ++rt)
                        axn[nt][rt] = __builtin_amdgcn_mfma_f32_16x16x32_bf16(
                            a0[rt], b, axn[nt][rt], 0, 0, 0);
                }
#pragma unroll
                for (int t = 0; t < 4; ++t) {
                    bf16x8 b = *reinterpret_cast<const bf16x8*>(bq1 + t * 512);
#pragma unroll
                    for (int rt = 0; rt < 4; ++rt)
                        arz[t][rt] = __builtin_amdgcn_mfma_f32_16x16x32_bf16(
                            a1[rt], b, arz[t][rt], 0, 0, 0);
                }
#pragma unroll
                for (int nt = 0; nt < 2; ++nt) {
                    bf16x8 b = *reinterpret_cast<const bf16x8*>(bh + nt * 512);
#pragma unroll
                    for (int rt = 0; rt < 4; ++rt)
                        ahn[nt][rt] = __builtin_amdgcn_mfma_f32_16x16x32_bf16(
                            a1[rt], b, ahn[nt][rt], 0, 0, 0);
                }
                bq0 += 4 * 512;
                bq1 += 4 * 512;
                bx += 2 * 512;
                bh += 2 * 512;
            }
            __syncthreads();
#pragma unroll
            for (int nt = 0; nt < 2; ++nt) {
                int col = nt ? cB : cA;
#pragma unroll
                for (int rt = 0; rt < 4; ++rt)
#pragma unroll
                    for (int r = 0; r < 4; ++r) {
                        int row = rt * 16 + quad * 4 + r;
                        float rr = fast_sigmoid(arz[nt][rt][r]);
                        float zz = fast_sigmoid(arz[2 + nt][rt][r]);
                        float nn =
                            fast_tanh(axn[nt][rt][r] + rr * ahn[nt][rt][r]);
                        float hold = bf2f(h1s[row * 264 + col]);
                        h1s[row * 264 + col] = f2bf((1.f - zz) * nn + zz * hold);
                    }
            }
        }
        __syncthreads();

        {
            int brow = tid >> 3, p = tid & 7;
            float d0 = 0.f, d1 = 0.f;
#pragma unroll
            for (int j = 0; j < 4; ++j) {
                int cb = ((p + brow) & 7) * 8 + j * 64;
                bf16x8 hv8 = *reinterpret_cast<const bf16x8*>(h1s + brow * 264 + cb);
#pragma unroll
                for (int i = 0; i < 8; ++i) {
                    float hv = bf2f(hv8[i]);
                    d0 += hv * owl[cb + i];
                    d1 += hv * owl[256 + cb + i];
                }
            }
            d0 += __shfl_xor(d0, 1); d0 += __shfl_xor(d0, 2); d0 += __shfl_xor(d0, 4);
            d1 += __shfl_xor(d1, 1); d1 += __shfl_xor(d1, 2); d1 += __shfl_xor(d1, 4);
            d0 += ob0v;
            d1 += ob1v;
            if (p == 0) {
                cum0 += d0;
                cum1 += d1;
                size_t o = (((size_t)(b0 + brow) * 3 + m) * (size_t)T + st) * 2;
                out[o] = cum0;
                out[o + 1] = cum1;
                posD[brow * 2] = d0;
                posD[brow * 2 + 1] = d1;
            }
        }
        __syncthreads();
    }
}

extern "C" void kernel_launch(void* const* d_in, const int* in_sizes, int n_in,
                              void* d_out, int out_size, void* d_ws, size_t ws_size,
                              hipStream_t stream) {
    const float* context = (const float*)d_in[0];
    const float* mp_w1 = (const float*)d_in[1];
    const float* mp_b1 = (const float*)d_in[2];
    const float* mp_w2 = (const float*)d_in[3];
    const float* mp_b2 = (const float*)d_in[4];
    const float* w_ih0 = (const float*)d_in[5];
    const float* w_hh0 = (const float*)d_in[6];
    const float* b_ih0 = (const float*)d_in[7];
    const float* b_hh0 = (const float*)d_in[8];
    const float* w_ih1 = (const float*)d_in[9];
    const float* w_hh1 = (const float*)d_in[10];
    const float* b_ih1 = (const float*)d_in[11];
    const float* b_hh1 = (const float*)d_in[12];
    const float* out_w = (const float*)d_in[13];
    const float* out_b = (const float*)d_in[14];
    const int* pT = (const int*)d_in[15];
    float* out = (float*)d_out;
    short* ws = (short*)d_ws;

    const int B = in_sizes[0] / 256;                      // 4096
    const int ntiles = B / 64;                            // 64
    const long probs_off = (long)out_size - (long)B * 3;

    prep_kernel<<<4608, 64, 0, stream>>>(w_ih0, w_hh0, w_ih1, w_hh1, ws);
    modeprobs_kernel<<<B / 64, 256, 0, stream>>>(context, mp_w1, mp_b1, mp_w2,
                                                 mp_b2, out, probs_off);
    const int nslots = (ntiles + 1) / 2;

    // gxc_xn cache: prep region + 3*ntiles blocks * 8 waves * 8 tiles * 256
    // shorts. Guard against OOB ws writes.
    const size_t needed =
        ((size_t)4608 * 512 + (size_t)3 * ntiles * 8 * 8 * 256) * sizeof(short);
    if (ws_size >= needed) {
        decoder_gxc2<<<8 * nslots, 512, 0, stream>>>(
            context, w_ih0, b_ih0, b_hh0, b_ih1, b_hh1, out_w, out_b, ws, out,
            pT, ntiles);
    } else {
        decoder_base<<<8 * nslots, 512, 0, stream>>>(
            context, w_ih0, b_ih0, b_hh0, b_ih1, b_hh1, out_w, out_b, ws, out,
            pT, ntiles);
    }
}